// Round 1
// baseline (1456.611 us; speedup 1.0000x reference)
//
#include <hip/hip_runtime.h>

#define LDIM 320
#define CZ 128
#define NH 4
#define CH 32
#define SCALE_QK 0.17677669529663687f  // 1/sqrt(32)
#define LN_EPS 1e-5f

__device__ __forceinline__ unsigned int pack_bf2(float a, float b) {
  unsigned int ua = __float_as_uint(a);
  unsigned int ub = __float_as_uint(b);
  unsigned int ra = (ua + 0x7fffu + ((ua >> 16) & 1u)) >> 16;   // RNE bf16
  unsigned int rb = (ub + 0x7fffu + ((ub >> 16) & 1u)) >> 16;
  return (ra & 0xffffu) | (rb << 16);
}

// ---------------------------------------------------------------------------
// Kernel 1: fused LayerNorm + Q/K/V/G/B projections.
// GEMM M=102400 (64-tiles), K=128, N=516 padded to 576 (9 tiles of 64).
// As stored transposed [k][m] fp32, Bs [k][n] fp32 -> 64KB LDS, 2 blocks/CU.
// ---------------------------------------------------------------------------
__global__ __launch_bounds__(256) void k_lnproj(
    const float* __restrict__ z, const float* __restrict__ gamma,
    const float* __restrict__ beta,
    const float* __restrict__ Wq, const float* __restrict__ Wk,
    const float* __restrict__ Wv, const float* __restrict__ Wb,
    const float* __restrict__ Wg,
    float* __restrict__ Qb, float* __restrict__ Kb, float* __restrict__ Vb,
    float* __restrict__ Gb, float* __restrict__ Bbias)
{
  __shared__ float As[128 * 64];  // [k][m]
  __shared__ float Bs[128 * 64];  // [k][n]
  const int t = threadIdx.x;
  const int ntile = blockIdx.x;        // 0..8
  const int m0 = blockIdx.y * 64;

  // ---- stage A tile with fused LayerNorm (4 lanes per row) ----
  {
    const int r = t >> 2, qt = t & 3;
    float x[32];
    const float* zp = z + (size_t)(m0 + r) * CZ + qt * 32;
#pragma unroll
    for (int ii = 0; ii < 8; ++ii) {
      float4 v = *(const float4*)(zp + ii * 4);
      x[ii * 4 + 0] = v.x; x[ii * 4 + 1] = v.y;
      x[ii * 4 + 2] = v.z; x[ii * 4 + 3] = v.w;
    }
    float s = 0.f, ss = 0.f;
#pragma unroll
    for (int c = 0; c < 32; ++c) { s += x[c]; ss += x[c] * x[c]; }
    s  += __shfl_xor(s, 1);  ss += __shfl_xor(ss, 1);
    s  += __shfl_xor(s, 2);  ss += __shfl_xor(ss, 2);
    const float mu  = s * (1.f / 128.f);
    const float var = ss * (1.f / 128.f) - mu * mu;
    const float rs  = rsqrtf(var + LN_EPS);
#pragma unroll
    for (int c = 0; c < 32; ++c) {
      const int ch = qt * 32 + c;
      const float y = (x[c] - mu) * rs * gamma[ch] + beta[ch];
      As[ch * 64 + r] = y;   // transposed store
    }
  }
  // ---- stage B tile (concatenated weight columns) ----
  {
    const int nl = t & 63, k0 = t >> 6;
    const int ng = ntile * 64 + nl;
#pragma unroll 4
    for (int it = 0; it < 32; ++it) {
      const int k = it * 4 + k0;
      float v;
      if (ng < 128)      v = Wq[k * 128 + ng];
      else if (ng < 256) v = Wk[k * 128 + ng - 128];
      else if (ng < 384) v = Wv[k * 128 + ng - 256];
      else if (ng < 512) v = Wg[k * 128 + ng - 384];
      else if (ng < 516) v = Wb[k * 4 + ng - 512];
      else               v = 0.f;
      Bs[k * 64 + nl] = v;
    }
  }
  __syncthreads();

  const int tx = t & 15, ty = t >> 4;
  float acc[4][4];
#pragma unroll
  for (int i = 0; i < 4; ++i)
#pragma unroll
    for (int j = 0; j < 4; ++j) acc[i][j] = 0.f;

#pragma unroll 4
  for (int k = 0; k < 128; ++k) {
    const float4 a4 = *(const float4*)&As[k * 64 + ty * 4];
    const float4 b4 = *(const float4*)&Bs[k * 64 + tx * 4];
    const float a[4] = {a4.x, a4.y, a4.z, a4.w};
    const float b[4] = {b4.x, b4.y, b4.z, b4.w};
#pragma unroll
    for (int i = 0; i < 4; ++i)
#pragma unroll
      for (int j = 0; j < 4; ++j) acc[i][j] += a[i] * b[j];
  }

  const int n0 = ntile * 64 + tx * 4;
#pragma unroll
  for (int i = 0; i < 4; ++i) {
    const int p = m0 + ty * 4 + i;
    float4 v;
    v.x = acc[i][0]; v.y = acc[i][1]; v.z = acc[i][2]; v.w = acc[i][3];
    if (n0 < 128) {
      *(float4*)&Qb[(size_t)p * 128 + n0] = v;
    } else if (n0 < 256) {
      *(float4*)&Kb[(size_t)p * 128 + (n0 - 128)] = v;
    } else if (n0 < 384) {
      *(float4*)&Vb[(size_t)p * 128 + (n0 - 256)] = v;
    } else if (n0 < 512) {
      float4 g;
      g.x = 1.f / (1.f + __expf(-v.x));
      g.y = 1.f / (1.f + __expf(-v.y));
      g.z = 1.f / (1.f + __expf(-v.z));
      g.w = 1.f / (1.f + __expf(-v.w));
      *(float4*)&Gb[(size_t)p * 128 + (n0 - 384)] = g;
    } else if (n0 < 516) {
      *(float4*)&Bbias[(size_t)p * 4] = v;   // only tx==0 lands here
    }
  }
}

// ---------------------------------------------------------------------------
// Kernel 2: attention per (i,h). K/V in LDS as packed bf16.
// Each wave handles j-pairs; gate applied and written in-place over Gb.
// ---------------------------------------------------------------------------
__global__ __launch_bounds__(256) void k_attn(
    const float* __restrict__ Qb, const float* __restrict__ Kb,
    const float* __restrict__ Vb, const float* __restrict__ Bbias,
    float* __restrict__ Gb, const int* __restrict__ rmask)
{
  __shared__ unsigned int Ks[320 * 17];   // [k][c2], bf16 pairs, pad 17
  __shared__ unsigned int Vs[320 * 17];
  __shared__ float pbuf[4][2][321];
  __shared__ float qbuf[4][2][32];
  const int h = blockIdx.x, i = blockIdx.y;
  const int t = threadIdx.x;

  // ---- stage K,V (fp32 global -> bf16 LDS) ----
  {
    const int krow = t >> 3, c4 = (t & 7) * 4;
    for (int it = 0; it < 10; ++it) {
      const int k = krow + 32 * it;
      const size_t gbase = (size_t)(i * LDIM + k) * CZ + h * CH + c4;
      const float4 kv = *(const float4*)&Kb[gbase];
      const float4 vv = *(const float4*)&Vb[gbase];
      Ks[k * 17 + (c4 >> 1)]     = pack_bf2(kv.x, kv.y);
      Ks[k * 17 + (c4 >> 1) + 1] = pack_bf2(kv.z, kv.w);
      Vs[k * 17 + (c4 >> 1)]     = pack_bf2(vv.x, vv.y);
      Vs[k * 17 + (c4 >> 1) + 1] = pack_bf2(vv.z, vv.w);
    }
  }
  __syncthreads();

  const int w = t >> 6, lane = t & 63;
  int km[5];
#pragma unroll
  for (int t5 = 0; t5 < 5; ++t5) km[t5] = rmask[t5 * 64 + lane];

  for (int pi = w; pi < 160; pi += 4) {
    const int j0 = pi * 2, j1 = j0 + 1;
    // stage Q rows for this pair through LDS (broadcast source)
    if (lane < 32)
      qbuf[w][0][lane] = Qb[(size_t)(i * LDIM + j0) * CZ + h * CH + lane];
    else
      qbuf[w][1][lane - 32] = Qb[(size_t)(i * LDIM + j1) * CZ + h * CH + (lane - 32)];
    float q0[32], q1[32];
#pragma unroll
    for (int c = 0; c < 32; ++c) { q0[c] = qbuf[w][0][c]; q1[c] = qbuf[w][1][c]; }

    // ---- QK^T: lane owns k = t5*64 + lane ----
    float s0[5], s1[5];
#pragma unroll
    for (int t5 = 0; t5 < 5; ++t5) { s0[t5] = 0.f; s1[t5] = 0.f; }
#pragma unroll
    for (int t5 = 0; t5 < 5; ++t5) {
      const int k = t5 * 64 + lane;
      const unsigned int* kr = &Ks[k * 17];
#pragma unroll
      for (int c2 = 0; c2 < 16; ++c2) {
        const unsigned int u = kr[c2];
        const float klo = __uint_as_float(u << 16);
        const float khi = __uint_as_float(u & 0xffff0000u);
        s0[t5] += q0[2 * c2] * klo; s0[t5] += q0[2 * c2 + 1] * khi;
        s1[t5] += q1[2 * c2] * klo; s1[t5] += q1[2 * c2 + 1] * khi;
      }
    }
    // bias + scale + mask, row max
    float m0v = -INFINITY, m1v = -INFINITY;
#pragma unroll
    for (int t5 = 0; t5 < 5; ++t5) {
      const int k = t5 * 64 + lane;
      const float b0 = Bbias[(size_t)(j0 * LDIM + k) * NH + h];
      const float b1 = Bbias[(size_t)(j1 * LDIM + k) * NH + h];
      s0[t5] = km[t5] ? s0[t5] * SCALE_QK + b0 : -INFINITY;
      s1[t5] = km[t5] ? s1[t5] * SCALE_QK + b1 : -INFINITY;
      m0v = fmaxf(m0v, s0[t5]); m1v = fmaxf(m1v, s1[t5]);
    }
#pragma unroll
    for (int off = 32; off; off >>= 1) {
      m0v = fmaxf(m0v, __shfl_xor(m0v, off));
      m1v = fmaxf(m1v, __shfl_xor(m1v, off));
    }
    float l0 = 0.f, l1 = 0.f;
#pragma unroll
    for (int t5 = 0; t5 < 5; ++t5) {
      const int k = t5 * 64 + lane;
      const float p0 = (s0[t5] == -INFINITY) ? 0.f : __expf(s0[t5] - m0v);
      const float p1 = (s1[t5] == -INFINITY) ? 0.f : __expf(s1[t5] - m1v);
      pbuf[w][0][k] = p0; pbuf[w][1][k] = p1;
      l0 += p0; l1 += p1;
    }
#pragma unroll
    for (int off = 32; off; off >>= 1) {
      l0 += __shfl_xor(l0, off);
      l1 += __shfl_xor(l1, off);
    }
    const float rl0 = (l0 > 0.f) ? 1.f / l0 : 0.f;
    const float rl1 = (l1 > 0.f) ? 1.f / l1 : 0.f;

    // ---- P·V: lane -> channels {2*c2, 2*c2+1}, k-quarter qq ----
    const int c2 = lane & 15, qq = lane >> 4;
    float o0a = 0.f, o0b = 0.f, o1a = 0.f, o1b = 0.f;
    const float* p0r = &pbuf[w][0][qq * 80];
    const float* p1r = &pbuf[w][1][qq * 80];
#pragma unroll 8
    for (int kk = 0; kk < 80; ++kk) {
      const int k = qq * 80 + kk;
      const unsigned int u = Vs[k * 17 + c2];
      const float vlo = __uint_as_float(u << 16);
      const float vhi = __uint_as_float(u & 0xffff0000u);
      const float p0 = p0r[kk], p1 = p1r[kk];
      o0a += p0 * vlo; o0b += p0 * vhi;
      o1a += p1 * vlo; o1b += p1 * vhi;
    }
    o0a += __shfl_xor(o0a, 16); o0a += __shfl_xor(o0a, 32);
    o0b += __shfl_xor(o0b, 16); o0b += __shfl_xor(o0b, 32);
    o1a += __shfl_xor(o1a, 16); o1a += __shfl_xor(o1a, 32);
    o1b += __shfl_xor(o1b, 16); o1b += __shfl_xor(o1b, 32);

    if (qq < 2) {
      const int j = qq ? j1 : j0;
      const float oa = qq ? o1a * rl1 : o0a * rl0;
      const float ob = qq ? o1b * rl1 : o0b * rl0;
      float* gp = &Gb[(size_t)(i * LDIM + j) * CZ + h * CH + 2 * c2];
      const float gx = gp[0], gy = gp[1];
      gp[0] = gx * oa;   // gate applied, stored in-place over G
      gp[1] = gy * ob;
    }
  }
}

// ---------------------------------------------------------------------------
// Kernel 3: output GEMM  dz = (G .* O) @ Wout, * pair_mask
// ---------------------------------------------------------------------------
__global__ __launch_bounds__(256) void k_out(
    const float* __restrict__ Gb, const float* __restrict__ Wout,
    const float* __restrict__ pm, float* __restrict__ out)
{
  __shared__ float As[128 * 64];  // [k][m]
  __shared__ float Bs[128 * 64];  // [k][n]
  const int t = threadIdx.x;
  const int ntile = blockIdx.x;   // 0..1
  const int m0 = blockIdx.y * 64;

  {
    const int r = t >> 2, qt = t & 3;
    const float* gp = Gb + (size_t)(m0 + r) * CZ + qt * 32;
#pragma unroll
    for (int ii = 0; ii < 8; ++ii) {
      float4 v = *(const float4*)(gp + ii * 4);
      As[(qt * 32 + ii * 4 + 0) * 64 + r] = v.x;
      As[(qt * 32 + ii * 4 + 1) * 64 + r] = v.y;
      As[(qt * 32 + ii * 4 + 2) * 64 + r] = v.z;
      As[(qt * 32 + ii * 4 + 3) * 64 + r] = v.w;
    }
  }
  {
    const int nl = t & 63, k0 = t >> 6;
    const int ng = ntile * 64 + nl;
#pragma unroll 4
    for (int it = 0; it < 32; ++it) {
      const int k = it * 4 + k0;
      Bs[k * 64 + nl] = Wout[k * 128 + ng];
    }
  }
  __syncthreads();

  const int tx = t & 15, ty = t >> 4;
  float acc[4][4];
#pragma unroll
  for (int i = 0; i < 4; ++i)
#pragma unroll
    for (int j = 0; j < 4; ++j) acc[i][j] = 0.f;

#pragma unroll 4
  for (int k = 0; k < 128; ++k) {
    const float4 a4 = *(const float4*)&As[k * 64 + ty * 4];
    const float4 b4 = *(const float4*)&Bs[k * 64 + tx * 4];
    const float a[4] = {a4.x, a4.y, a4.z, a4.w};
    const float b[4] = {b4.x, b4.y, b4.z, b4.w};
#pragma unroll
    for (int i = 0; i < 4; ++i)
#pragma unroll
      for (int j = 0; j < 4; ++j) acc[i][j] += a[i] * b[j];
  }

  const int n0 = ntile * 64 + tx * 4;
#pragma unroll
  for (int i = 0; i < 4; ++i) {
    const int p = m0 + ty * 4 + i;
    const float m = pm[p];
    float4 v;
    v.x = acc[i][0] * m; v.y = acc[i][1] * m;
    v.z = acc[i][2] * m; v.w = acc[i][3] * m;
    *(float4*)&out[(size_t)p * 128 + n0] = v;
  }
}

// ---------------------------------------------------------------------------
extern "C" void kernel_launch(void* const* d_in, const int* in_sizes, int n_in,
                              void* d_out, int out_size, void* d_ws, size_t ws_size,
                              hipStream_t stream)
{
  const float* z     = (const float*)d_in[0];
  const float* pmask = (const float*)d_in[1];
  const int*   rmask = (const int*)d_in[2];
  const float* gamma = (const float*)d_in[3];
  const float* beta  = (const float*)d_in[4];
  const float* Wq    = (const float*)d_in[5];
  const float* Wk    = (const float*)d_in[6];
  const float* Wv    = (const float*)d_in[7];
  const float* Wb    = (const float*)d_in[8];
  const float* Wg    = (const float*)d_in[9];
  const float* Wout  = (const float*)d_in[10];

  const size_t P = (size_t)LDIM * LDIM;   // 102400
  float* ws = (float*)d_ws;
  float* Qb    = ws;
  float* Kb    = Qb + P * 128;
  float* Vb    = Kb + P * 128;
  float* Gb    = Vb + P * 128;            // becomes gated attention output
  float* Bbias = Gb + P * 128;            // P*4 floats

  k_lnproj<<<dim3(9, 1600), 256, 0, stream>>>(z, gamma, beta, Wq, Wk, Wv, Wb, Wg,
                                              Qb, Kb, Vb, Gb, Bbias);
  k_attn<<<dim3(NH, LDIM), 256, 0, stream>>>(Qb, Kb, Vb, Bbias, Gb, rmask);
  k_out<<<dim3(2, 1600), 256, 0, stream>>>(Gb, Wout, pmask, (float*)d_out);
}

// Round 3
// 727.127 us; speedup vs baseline: 2.0032x; 2.0032x over previous
//
#include <hip/hip_runtime.h>

#define LDIM 320
#define CZ 128
#define NH 4
#define CH 32
#define SCALE_QK 0.17677669529663687f  // 1/sqrt(32)
#define LN_EPS 1e-5f

typedef __attribute__((ext_vector_type(8))) short bf16x8;
typedef __attribute__((ext_vector_type(4))) float f32x4;

__device__ __forceinline__ unsigned int pack_bf2(float a, float b) {
  unsigned int ua = __float_as_uint(a);
  unsigned int ub = __float_as_uint(b);
  unsigned int ra = (ua + 0x7fffu + ((ua >> 16) & 1u)) >> 16;   // RNE bf16
  unsigned int rb = (ub + 0x7fffu + ((ub >> 16) & 1u)) >> 16;
  return (ra & 0xffffu) | (rb << 16);
}

__device__ __forceinline__ unsigned short f2bf(float a) {
  unsigned int ua = __float_as_uint(a);
  return (unsigned short)((ua + 0x7fffu + ((ua >> 16) & 1u)) >> 16);
}

__device__ __forceinline__ float bf2f(unsigned short u) {
  return __uint_as_float(((unsigned int)u) << 16);
}

// ---------------------------------------------------------------------------
// Kernel 1: fused LayerNorm + Q/K/V/G/B projections (fp32 VALU GEMM core).
// Outputs: Qg/Kg/Vg/Gg bf16 in [i][h][row][c] layout; Bh fp32 [h][j*320+k].
// ---------------------------------------------------------------------------
__global__ __launch_bounds__(256) void k_lnproj(
    const float* __restrict__ z, const float* __restrict__ gamma,
    const float* __restrict__ beta,
    const float* __restrict__ Wq, const float* __restrict__ Wk,
    const float* __restrict__ Wv, const float* __restrict__ Wb,
    const float* __restrict__ Wg,
    unsigned short* __restrict__ Qg, unsigned short* __restrict__ Kg,
    unsigned short* __restrict__ Vg, unsigned short* __restrict__ Gg,
    float* __restrict__ Bh)
{
  __shared__ float As[128 * 64];  // [k][m]
  __shared__ float Bs[128 * 64];  // [k][n]
  const int t = threadIdx.x;
  const int ntile = blockIdx.x;        // 0..8
  const int m0 = blockIdx.y * 64;

  // ---- stage A tile with fused LayerNorm (4 lanes per row) ----
  {
    const int r = t >> 2, qt = t & 3;
    float x[32];
    const float* zp = z + (size_t)(m0 + r) * CZ + qt * 32;
#pragma unroll
    for (int ii = 0; ii < 8; ++ii) {
      float4 v = *(const float4*)(zp + ii * 4);
      x[ii * 4 + 0] = v.x; x[ii * 4 + 1] = v.y;
      x[ii * 4 + 2] = v.z; x[ii * 4 + 3] = v.w;
    }
    float s = 0.f, ss = 0.f;
#pragma unroll
    for (int c = 0; c < 32; ++c) { s += x[c]; ss += x[c] * x[c]; }
    s  += __shfl_xor(s, 1);  ss += __shfl_xor(ss, 1);
    s  += __shfl_xor(s, 2);  ss += __shfl_xor(ss, 2);
    const float mu  = s * (1.f / 128.f);
    const float var = ss * (1.f / 128.f) - mu * mu;
    const float rs  = rsqrtf(var + LN_EPS);
#pragma unroll
    for (int c = 0; c < 32; ++c) {
      const int ch = qt * 32 + c;
      const float y = (x[c] - mu) * rs * gamma[ch] + beta[ch];
      As[ch * 64 + r] = y;   // transposed store
    }
  }
  // ---- stage B tile (concatenated weight columns) ----
  {
    const int nl = t & 63, k0 = t >> 6;
    const int ng = ntile * 64 + nl;
#pragma unroll 4
    for (int it = 0; it < 32; ++it) {
      const int k = it * 4 + k0;
      float v;
      if (ng < 128)      v = Wq[k * 128 + ng];
      else if (ng < 256) v = Wk[k * 128 + ng - 128];
      else if (ng < 384) v = Wv[k * 128 + ng - 256];
      else if (ng < 512) v = Wg[k * 128 + ng - 384];
      else if (ng < 516) v = Wb[k * 4 + ng - 512];
      else               v = 0.f;
      Bs[k * 64 + nl] = v;
    }
  }
  __syncthreads();

  const int tx = t & 15, ty = t >> 4;
  float acc[4][4];
#pragma unroll
  for (int i = 0; i < 4; ++i)
#pragma unroll
    for (int j = 0; j < 4; ++j) acc[i][j] = 0.f;

#pragma unroll 4
  for (int k = 0; k < 128; ++k) {
    const float4 a4 = *(const float4*)&As[k * 64 + ty * 4];
    const float4 b4 = *(const float4*)&Bs[k * 64 + tx * 4];
    const float a[4] = {a4.x, a4.y, a4.z, a4.w};
    const float b[4] = {b4.x, b4.y, b4.z, b4.w};
#pragma unroll
    for (int i = 0; i < 4; ++i)
#pragma unroll
      for (int j = 0; j < 4; ++j) acc[i][j] += a[i] * b[j];
  }

  const int n0 = ntile * 64 + tx * 4;
#pragma unroll
  for (int i = 0; i < 4; ++i) {
    const int p = m0 + ty * 4 + i;
    const int a = p / 320, bb = p - a * 320;
    if (n0 < 384) {
      const int sel = n0 >> 7;           // 0=Q,1=K,2=V
      const int off = n0 & 127, hh = off >> 5, cc = off & 31;
      unsigned short* dst = (sel == 0 ? Qg : (sel == 1 ? Kg : Vg));
      uint2 pk;
      pk.x = pack_bf2(acc[i][0], acc[i][1]);
      pk.y = pack_bf2(acc[i][2], acc[i][3]);
      *(uint2*)(dst + ((size_t)((a * 4 + hh) * 320 + bb) * 32 + cc)) = pk;
    } else if (n0 < 512) {
      const int off = n0 - 384, hh = off >> 5, cc = off & 31;
      float g0 = 1.f / (1.f + __expf(-acc[i][0]));
      float g1 = 1.f / (1.f + __expf(-acc[i][1]));
      float g2 = 1.f / (1.f + __expf(-acc[i][2]));
      float g3 = 1.f / (1.f + __expf(-acc[i][3]));
      uint2 pk;
      pk.x = pack_bf2(g0, g1);
      pk.y = pack_bf2(g2, g3);
      *(uint2*)(Gg + ((size_t)((a * 4 + hh) * 320 + bb) * 32 + cc)) = pk;
    } else if (n0 == 512) {
#pragma unroll
      for (int h2 = 0; h2 < 4; ++h2)
        Bh[(size_t)h2 * 102400 + p] = acc[i][h2];
    }
  }
}

// ---------------------------------------------------------------------------
// Kernel 2: MFMA attention. Block = (i,h), 4 waves; wave handles 5 j-tiles.
// K B-fragments read from global (L1/L2-resident, 20 KB/block).
// LDS: Vt (V transposed, bf16) + per-wave Ps (normalized P^ bf16) = 42.5 KB.
// ---------------------------------------------------------------------------
__global__ __launch_bounds__(256) void k_attn(
    const unsigned short* __restrict__ Qg, const unsigned short* __restrict__ Kg,
    const unsigned short* __restrict__ Vg, const unsigned short* __restrict__ Gg,
    const float* __restrict__ Bh, const int* __restrict__ rmask,
    float* __restrict__ Ob)
{
  __shared__ __attribute__((aligned(16))) unsigned short Vt[32 * 328];     // [c][k]
  __shared__ __attribute__((aligned(16))) unsigned short Ps[4][16 * 168];  // per-wave
  const int h = blockIdx.x, i = blockIdx.y;
  const int t = threadIdx.x;
  const size_t base = (size_t)(i * NH + h) * (LDIM * CH);

  // ---- stage V transposed [c][k] ----
  {
    const int k0 = t >> 3, c4 = (t & 7) * 4;
#pragma unroll
    for (int it = 0; it < 10; ++it) {
      const int k = k0 + 32 * it;
      const uint2 d = *(const uint2*)(Vg + base + k * 32 + c4);
      Vt[(c4 + 0) * 328 + k] = (unsigned short)(d.x & 0xffffu);
      Vt[(c4 + 1) * 328 + k] = (unsigned short)(d.x >> 16);
      Vt[(c4 + 2) * 328 + k] = (unsigned short)(d.y & 0xffffu);
      Vt[(c4 + 3) * 328 + k] = (unsigned short)(d.y >> 16);
    }
  }
  __syncthreads();

  const int w = t >> 6, lane = t & 63;
  const int m16 = lane & 15, qd = lane >> 4;
  const f32x4 z4 = {0.f, 0.f, 0.f, 0.f};

  float mkr[20];
#pragma unroll
  for (int kt = 0; kt < 20; ++kt)
    mkr[kt] = rmask[kt * 16 + m16] ? 0.f : -INFINITY;

  for (int jt = w; jt < 20; jt += 4) {
    // A-frag: Q rows from global (L2-resident)
    const bf16x8 qfrag =
        *(const bf16x8*)(Qg + base + (size_t)(jt * 16 + m16) * 32 + qd * 8);

    // ---- QK^T: 20 MFMAs; B-frags straight from global ----
    f32x4 acc[20];
#pragma unroll
    for (int kt = 0; kt < 20; ++kt) {
      const bf16x8 kf =
          *(const bf16x8*)(Kg + base + (size_t)(kt * 16 + m16) * 32 + qd * 8);
      acc[kt] = __builtin_amdgcn_mfma_f32_16x16x32_bf16(qfrag, kf, z4, 0, 0, 0);
    }

    // ---- scale + bias + mask, row max (C layout: row=qd*4+r, col=m16) ----
    const float* bp = Bh + (size_t)h * 102400 +
                      (size_t)(jt * 16 + qd * 4) * 320 + m16;
    float mx[4] = {-INFINITY, -INFINITY, -INFINITY, -INFINITY};
#pragma unroll
    for (int kt = 0; kt < 20; ++kt) {
#pragma unroll
      for (int r = 0; r < 4; ++r) {
        const float b = bp[r * 320 + kt * 16];
        const float s = fmaf(acc[kt][r], SCALE_QK, b) + mkr[kt];
        acc[kt][r] = s;
        mx[r] = fmaxf(mx[r], s);
      }
    }
#pragma unroll
    for (int r = 0; r < 4; ++r) {
      mx[r] = fmaxf(mx[r], __shfl_xor(mx[r], 1));
      mx[r] = fmaxf(mx[r], __shfl_xor(mx[r], 2));
      mx[r] = fmaxf(mx[r], __shfl_xor(mx[r], 4));
      mx[r] = fmaxf(mx[r], __shfl_xor(mx[r], 8));
    }
    // ---- exp + row sum ----
    float l[4] = {0.f, 0.f, 0.f, 0.f};
#pragma unroll
    for (int kt = 0; kt < 20; ++kt) {
#pragma unroll
      for (int r = 0; r < 4; ++r) {
        const float p = __expf(acc[kt][r] - mx[r]);
        acc[kt][r] = p;
        l[r] += p;
      }
    }
#pragma unroll
    for (int r = 0; r < 4; ++r) {
      l[r] += __shfl_xor(l[r], 1);
      l[r] += __shfl_xor(l[r], 2);
      l[r] += __shfl_xor(l[r], 4);
      l[r] += __shfl_xor(l[r], 8);
    }
    float rl[4];
#pragma unroll
    for (int r = 0; r < 4; ++r) rl[r] = 1.f / l[r];

    // ---- PV in two k-halves through per-wave LDS P^ buffer ----
    f32x4 accO0 = z4, accO1 = z4;
#pragma unroll
    for (int hh = 0; hh < 2; ++hh) {
      __syncthreads();
#pragma unroll
      for (int kt2 = 0; kt2 < 10; ++kt2) {
        const int kt = hh * 10 + kt2;
#pragma unroll
        for (int r = 0; r < 4; ++r)
          Ps[w][(qd * 4 + r) * 168 + kt2 * 16 + m16] = f2bf(acc[kt][r] * rl[r]);
      }
      __syncthreads();
#pragma unroll
      for (int ks = 0; ks < 5; ++ks) {
        const bf16x8 pf = *(const bf16x8*)&Ps[w][m16 * 168 + ks * 32 + qd * 8];
        const bf16x8 v0 =
            *(const bf16x8*)&Vt[m16 * 328 + hh * 160 + ks * 32 + qd * 8];
        const bf16x8 v1 =
            *(const bf16x8*)&Vt[(16 + m16) * 328 + hh * 160 + ks * 32 + qd * 8];
        accO0 = __builtin_amdgcn_mfma_f32_16x16x32_bf16(pf, v0, accO0, 0, 0, 0);
        accO1 = __builtin_amdgcn_mfma_f32_16x16x32_bf16(pf, v1, accO1, 0, 0, 0);
      }
    }

    // ---- epilogue: gate + store (C layout: row=qd*4+r -> j, col=m16 -> c) ----
#pragma unroll
    for (int r = 0; r < 4; ++r) {
      const int j = jt * 16 + qd * 4 + r;
      const float g0 = bf2f(Gg[base + (size_t)j * 32 + m16]);
      const float g1 = bf2f(Gg[base + (size_t)j * 32 + 16 + m16]);
      float* op = Ob + (size_t)(i * 320 + j) * 128 + h * 32;
      op[m16]      = g0 * accO0[r];
      op[16 + m16] = g1 * accO1[r];
    }
  }
}

// ---------------------------------------------------------------------------
// Kernel 3: output GEMM  dz = Ob @ Wout, * pair_mask
// ---------------------------------------------------------------------------
__global__ __launch_bounds__(256) void k_out(
    const float* __restrict__ Ob, const float* __restrict__ Wout,
    const float* __restrict__ pm, float* __restrict__ out)
{
  __shared__ float As[128 * 64];  // [k][m]
  __shared__ float Bs[128 * 64];  // [k][n]
  const int t = threadIdx.x;
  const int ntile = blockIdx.x;   // 0..1
  const int m0 = blockIdx.y * 64;

  {
    const int r = t >> 2, qt = t & 3;
    const float* gp = Ob + (size_t)(m0 + r) * CZ + qt * 32;
#pragma unroll
    for (int ii = 0; ii < 8; ++ii) {
      float4 v = *(const float4*)(gp + ii * 4);
      As[(qt * 32 + ii * 4 + 0) * 64 + r] = v.x;
      As[(qt * 32 + ii * 4 + 1) * 64 + r] = v.y;
      As[(qt * 32 + ii * 4 + 2) * 64 + r] = v.z;
      As[(qt * 32 + ii * 4 + 3) * 64 + r] = v.w;
    }
  }
  {
    const int nl = t & 63, k0 = t >> 6;
    const int ng = ntile * 64 + nl;
#pragma unroll 4
    for (int it = 0; it < 32; ++it) {
      const int k = it * 4 + k0;
      Bs[k * 64 + nl] = Wout[k * 128 + ng];
    }
  }
  __syncthreads();

  const int tx = t & 15, ty = t >> 4;
  float acc[4][4];
#pragma unroll
  for (int i = 0; i < 4; ++i)
#pragma unroll
    for (int j = 0; j < 4; ++j) acc[i][j] = 0.f;

#pragma unroll 4
  for (int k = 0; k < 128; ++k) {
    const float4 a4 = *(const float4*)&As[k * 64 + ty * 4];
    const float4 b4 = *(const float4*)&Bs[k * 64 + tx * 4];
    const float a[4] = {a4.x, a4.y, a4.z, a4.w};
    const float b[4] = {b4.x, b4.y, b4.z, b4.w};
#pragma unroll
    for (int i = 0; i < 4; ++i)
#pragma unroll
      for (int j = 0; j < 4; ++j) acc[i][j] += a[i] * b[j];
  }

  const int n0 = ntile * 64 + tx * 4;
#pragma unroll
  for (int i = 0; i < 4; ++i) {
    const int p = m0 + ty * 4 + i;
    const float m = pm[p];
    float4 v;
    v.x = acc[i][0] * m; v.y = acc[i][1] * m;
    v.z = acc[i][2] * m; v.w = acc[i][3] * m;
    *(float4*)&out[(size_t)p * 128 + n0] = v;
  }
}

// ---------------------------------------------------------------------------
extern "C" void kernel_launch(void* const* d_in, const int* in_sizes, int n_in,
                              void* d_out, int out_size, void* d_ws, size_t ws_size,
                              hipStream_t stream)
{
  const float* z     = (const float*)d_in[0];
  const float* pmask = (const float*)d_in[1];
  const int*   rmask = (const int*)d_in[2];
  const float* gamma = (const float*)d_in[3];
  const float* beta  = (const float*)d_in[4];
  const float* Wq    = (const float*)d_in[5];
  const float* Wk    = (const float*)d_in[6];
  const float* Wv    = (const float*)d_in[7];
  const float* Wb    = (const float*)d_in[8];
  const float* Wg    = (const float*)d_in[9];
  const float* Wout  = (const float*)d_in[10];

  const size_t P = (size_t)LDIM * LDIM;        // 102400
  const size_t E = P * 128;                    // 13,107,200 elements
  char* ws = (char*)d_ws;
  unsigned short* Qg = (unsigned short*)ws;              // E bf16
  unsigned short* Kg = Qg + E;
  unsigned short* Vg = Kg + E;
  unsigned short* Gg = Vg + E;
  float* Bh = (float*)(Gg + E);                          // 4*P fp32
  float* Ob = Bh + 4 * P;                                // E fp32

  k_lnproj<<<dim3(9, 1600), 256, 0, stream>>>(z, gamma, beta, Wq, Wk, Wv, Wb, Wg,
                                              Qg, Kg, Vg, Gg, Bh);
  k_attn<<<dim3(NH, LDIM), 256, 0, stream>>>(Qg, Kg, Vg, Gg, Bh, rmask, Ob);
  k_out<<<dim3(2, 1600), 256, 0, stream>>>(Ob, Wout, pmask, (float*)d_out);
}

// Round 4
// 405.038 us; speedup vs baseline: 3.5962x; 1.7952x over previous
//
#include <hip/hip_runtime.h>

#define LDIM 320
#define CZ 128
#define NH 4
#define CH 32
#define SCALE_QK 0.17677669529663687f  // 1/sqrt(32)
#define LN_EPS 1e-5f

typedef __attribute__((ext_vector_type(8))) short bf16x8;
typedef __attribute__((ext_vector_type(4))) float f32x4;

__device__ __forceinline__ unsigned int pack_bf2(float a, float b) {
  unsigned int ua = __float_as_uint(a);
  unsigned int ub = __float_as_uint(b);
  unsigned int ra = (ua + 0x7fffu + ((ua >> 16) & 1u)) >> 16;   // RNE bf16
  unsigned int rb = (ub + 0x7fffu + ((ub >> 16) & 1u)) >> 16;
  return (ra & 0xffffu) | (rb << 16);
}

__device__ __forceinline__ unsigned short f2bf(float a) {
  unsigned int ua = __float_as_uint(a);
  return (unsigned short)((ua + 0x7fffu + ((ua >> 16) & 1u)) >> 16);
}

__device__ __forceinline__ float bf2f(unsigned short u) {
  return __uint_as_float(((unsigned int)u) << 16);
}

// ---------------------------------------------------------------------------
// Kernel 0: weight prep. Wt[576][128] bf16 = [Wq|Wk|Wv|Wg|Wb|0] transposed;
// Woutt[128][128] bf16 = Wout transposed. Runs once per launch (11 blocks).
// ---------------------------------------------------------------------------
__global__ __launch_bounds__(256) void k_prep(
    const float* __restrict__ Wq, const float* __restrict__ Wk,
    const float* __restrict__ Wv, const float* __restrict__ Wb,
    const float* __restrict__ Wg, const float* __restrict__ Wout,
    unsigned short* __restrict__ Wt, unsigned short* __restrict__ Woutt)
{
  __shared__ __attribute__((aligned(16))) unsigned short buf[64 * 136];
  const int t = threadIdx.x, bid = blockIdx.x;
  const bool isOut = (bid >= 9);
  const int n0 = isOut ? (bid - 9) * 64 : bid * 64;
  const int nl = t & 63;
  const int n = n0 + nl;
#pragma unroll 8
  for (int it = 0; it < 32; ++it) {
    const int k = (t >> 6) + 4 * it;
    float v;
    if (isOut)        v = Wout[k * 128 + n];
    else if (n < 128) v = Wq[k * 128 + n];
    else if (n < 256) v = Wk[k * 128 + n - 128];
    else if (n < 384) v = Wv[k * 128 + n - 256];
    else if (n < 512) v = Wg[k * 128 + n - 384];
    else if (n < 516) v = Wb[k * 4 + n - 512];
    else              v = 0.f;
    buf[nl * 136 + k] = f2bf(v);
  }
  __syncthreads();
  unsigned short* dst = isOut ? Woutt : Wt;
#pragma unroll
  for (int it = 0; it < 4; ++it) {
    const int idx = t + 256 * it;
    const int rr = idx >> 4, ck = idx & 15;
    const uint4 d = *(const uint4*)&buf[rr * 136 + ck * 8];
    *(uint4*)(dst + (size_t)(n0 + rr) * 128 + ck * 8) = d;
  }
}

// ---------------------------------------------------------------------------
// Kernel 1: fused LayerNorm + all projections, bf16 MFMA GEMM.
// M-tile 128, N-tile 64 (grid 9 x 800). ntile 0-7: Q/K/V/G; ntile 8: bias.
// A staged with LN fused (2 lanes/row); frags per verified m92/attn pattern.
// ---------------------------------------------------------------------------
__global__ __launch_bounds__(256) void k_lnproj(
    const float* __restrict__ z, const float* __restrict__ gamma,
    const float* __restrict__ beta, const unsigned short* __restrict__ Wt,
    unsigned short* __restrict__ Qg, unsigned short* __restrict__ Kg,
    unsigned short* __restrict__ Vg, unsigned short* __restrict__ Gg,
    float* __restrict__ Bh)
{
  __shared__ __attribute__((aligned(16))) unsigned short As[128 * 136]; // 34.8KB
  __shared__ __attribute__((aligned(16))) unsigned short Bs[64 * 136];  // 17.4KB
  const int t = threadIdx.x;
  const int ntile = blockIdx.x;        // 0..8
  const int m0 = blockIdx.y * 128;

  // ---- stage A with fused LayerNorm: 2 lanes per row ----
  {
    const int r = t >> 1, half = t & 1;
    float x[64];
    const float* zp = z + (size_t)(m0 + r) * CZ + half * 64;
    float s = 0.f, ss = 0.f;
#pragma unroll
    for (int ii = 0; ii < 16; ++ii) {
      const float4 v = *(const float4*)(zp + ii * 4);
      x[ii * 4 + 0] = v.x; x[ii * 4 + 1] = v.y;
      x[ii * 4 + 2] = v.z; x[ii * 4 + 3] = v.w;
      s += v.x + v.y + v.z + v.w;
      ss += v.x * v.x + v.y * v.y + v.z * v.z + v.w * v.w;
    }
    s  += __shfl_xor(s, 1);
    ss += __shfl_xor(ss, 1);
    const float mu  = s * (1.f / 128.f);
    const float var = ss * (1.f / 128.f) - mu * mu;
    const float rs  = rsqrtf(var + LN_EPS);
    const float* gp = gamma + half * 64;
    const float* bp = beta + half * 64;
    unsigned int* As32 = (unsigned int*)As;
    const int dbase = r * 68 + half * 32;
#pragma unroll
    for (int q = 0; q < 8; ++q) {
      const float4 g0 = *(const float4*)(gp + q * 8);
      const float4 g1 = *(const float4*)(gp + q * 8 + 4);
      const float4 b0 = *(const float4*)(bp + q * 8);
      const float4 b1 = *(const float4*)(bp + q * 8 + 4);
      const float y0 = (x[q * 8 + 0] - mu) * rs * g0.x + b0.x;
      const float y1 = (x[q * 8 + 1] - mu) * rs * g0.y + b0.y;
      const float y2 = (x[q * 8 + 2] - mu) * rs * g0.z + b0.z;
      const float y3 = (x[q * 8 + 3] - mu) * rs * g0.w + b0.w;
      const float y4 = (x[q * 8 + 4] - mu) * rs * g1.x + b1.x;
      const float y5 = (x[q * 8 + 5] - mu) * rs * g1.y + b1.y;
      const float y6 = (x[q * 8 + 6] - mu) * rs * g1.z + b1.z;
      const float y7 = (x[q * 8 + 7] - mu) * rs * g1.w + b1.w;
      uint4 u;
      u.x = pack_bf2(y0, y1); u.y = pack_bf2(y2, y3);
      u.z = pack_bf2(y4, y5); u.w = pack_bf2(y6, y7);
      *(uint4*)&As32[dbase + q * 4] = u;
    }
  }
  // ---- stage B (pre-transposed weights, 16B chunks) ----
  {
    const unsigned short* wrow = Wt + (size_t)ntile * 64 * 128;
#pragma unroll
    for (int it = 0; it < 4; ++it) {
      const int idx = t + 256 * it;
      const int n = idx >> 4, ck = idx & 15;
      const uint4 d = *(const uint4*)(wrow + n * 128 + ck * 8);
      *(uint4*)&Bs[n * 136 + ck * 8] = d;
    }
  }
  __syncthreads();

  const int w = t >> 6, lane = t & 63;
  const int m16 = lane & 15, qd = lane >> 4;
  const f32x4 z4 = {0.f, 0.f, 0.f, 0.f};
  f32x4 acc[2][4];
#pragma unroll
  for (int sub = 0; sub < 2; ++sub)
#pragma unroll
    for (int nt = 0; nt < 4; ++nt) acc[sub][nt] = z4;

#pragma unroll
  for (int ks = 0; ks < 4; ++ks) {
    const bf16x8 af0 = *(const bf16x8*)&As[(w * 32 + m16) * 136 + qd * 8 + ks * 32];
    const bf16x8 af1 = *(const bf16x8*)&As[(w * 32 + 16 + m16) * 136 + qd * 8 + ks * 32];
#pragma unroll
    for (int nt = 0; nt < 4; ++nt) {
      const bf16x8 bf = *(const bf16x8*)&Bs[(nt * 16 + m16) * 136 + qd * 8 + ks * 32];
      acc[0][nt] = __builtin_amdgcn_mfma_f32_16x16x32_bf16(af0, bf, acc[0][nt], 0, 0, 0);
      acc[1][nt] = __builtin_amdgcn_mfma_f32_16x16x32_bf16(af1, bf, acc[1][nt], 0, 0, 0);
    }
  }

  // ---- epilogue: C row = qd*4+r -> p, col = m16 -> n ----
#pragma unroll
  for (int sub = 0; sub < 2; ++sub) {
#pragma unroll
    for (int r = 0; r < 4; ++r) {
      const int p = m0 + w * 32 + sub * 16 + qd * 4 + r;
      const int a = p / 320, bb = p - a * 320;
      if (ntile < 8) {
#pragma unroll
        for (int nt = 0; nt < 4; ++nt) {
          const int n = ntile * 64 + nt * 16 + m16;
          const int off = n & 127, hh = off >> 5, cc = off & 31;
          float val = acc[sub][nt][r];
          if (ntile >= 6) val = 1.f / (1.f + __expf(-val));  // sigmoid for G
          unsigned short* dst =
              (ntile < 2 ? Qg : (ntile < 4 ? Kg : (ntile < 6 ? Vg : Gg)));
          dst[((size_t)(a * 4 + hh) * 320 + bb) * 32 + cc] = f2bf(val);
        }
      } else {
        if (m16 < 4) Bh[(size_t)m16 * 102400 + p] = acc[sub][0][r];
      }
    }
  }
}

// ---------------------------------------------------------------------------
// Kernel 2: MFMA attention (verified round 3). Only change: Obg is bf16.
// ---------------------------------------------------------------------------
__global__ __launch_bounds__(256) void k_attn(
    const unsigned short* __restrict__ Qg, const unsigned short* __restrict__ Kg,
    const unsigned short* __restrict__ Vg, const unsigned short* __restrict__ Gg,
    const float* __restrict__ Bh, const int* __restrict__ rmask,
    unsigned short* __restrict__ Obg)
{
  __shared__ __attribute__((aligned(16))) unsigned short Vt[32 * 328];     // [c][k]
  __shared__ __attribute__((aligned(16))) unsigned short Ps[4][16 * 168];  // per-wave
  const int h = blockIdx.x, i = blockIdx.y;
  const int t = threadIdx.x;
  const size_t base = (size_t)(i * NH + h) * (LDIM * CH);

  // ---- stage V transposed [c][k] ----
  {
    const int k0 = t >> 3, c4 = (t & 7) * 4;
#pragma unroll
    for (int it = 0; it < 10; ++it) {
      const int k = k0 + 32 * it;
      const uint2 d = *(const uint2*)(Vg + base + k * 32 + c4);
      Vt[(c4 + 0) * 328 + k] = (unsigned short)(d.x & 0xffffu);
      Vt[(c4 + 1) * 328 + k] = (unsigned short)(d.x >> 16);
      Vt[(c4 + 2) * 328 + k] = (unsigned short)(d.y & 0xffffu);
      Vt[(c4 + 3) * 328 + k] = (unsigned short)(d.y >> 16);
    }
  }
  __syncthreads();

  const int w = t >> 6, lane = t & 63;
  const int m16 = lane & 15, qd = lane >> 4;
  const f32x4 z4 = {0.f, 0.f, 0.f, 0.f};

  float mkr[20];
#pragma unroll
  for (int kt = 0; kt < 20; ++kt)
    mkr[kt] = rmask[kt * 16 + m16] ? 0.f : -INFINITY;

  for (int jt = w; jt < 20; jt += 4) {
    const bf16x8 qfrag =
        *(const bf16x8*)(Qg + base + (size_t)(jt * 16 + m16) * 32 + qd * 8);

    f32x4 acc[20];
#pragma unroll
    for (int kt = 0; kt < 20; ++kt) {
      const bf16x8 kf =
          *(const bf16x8*)(Kg + base + (size_t)(kt * 16 + m16) * 32 + qd * 8);
      acc[kt] = __builtin_amdgcn_mfma_f32_16x16x32_bf16(qfrag, kf, z4, 0, 0, 0);
    }

    const float* bp = Bh + (size_t)h * 102400 +
                      (size_t)(jt * 16 + qd * 4) * 320 + m16;
    float mx[4] = {-INFINITY, -INFINITY, -INFINITY, -INFINITY};
#pragma unroll
    for (int kt = 0; kt < 20; ++kt) {
#pragma unroll
      for (int r = 0; r < 4; ++r) {
        const float b = bp[r * 320 + kt * 16];
        const float s = fmaf(acc[kt][r], SCALE_QK, b) + mkr[kt];
        acc[kt][r] = s;
        mx[r] = fmaxf(mx[r], s);
      }
    }
#pragma unroll
    for (int r = 0; r < 4; ++r) {
      mx[r] = fmaxf(mx[r], __shfl_xor(mx[r], 1));
      mx[r] = fmaxf(mx[r], __shfl_xor(mx[r], 2));
      mx[r] = fmaxf(mx[r], __shfl_xor(mx[r], 4));
      mx[r] = fmaxf(mx[r], __shfl_xor(mx[r], 8));
    }
    float l[4] = {0.f, 0.f, 0.f, 0.f};
#pragma unroll
    for (int kt = 0; kt < 20; ++kt) {
#pragma unroll
      for (int r = 0; r < 4; ++r) {
        const float p = __expf(acc[kt][r] - mx[r]);
        acc[kt][r] = p;
        l[r] += p;
      }
    }
#pragma unroll
    for (int r = 0; r < 4; ++r) {
      l[r] += __shfl_xor(l[r], 1);
      l[r] += __shfl_xor(l[r], 2);
      l[r] += __shfl_xor(l[r], 4);
      l[r] += __shfl_xor(l[r], 8);
    }
    float rl[4];
#pragma unroll
    for (int r = 0; r < 4; ++r) rl[r] = 1.f / l[r];

    f32x4 accO0 = z4, accO1 = z4;
#pragma unroll
    for (int hh = 0; hh < 2; ++hh) {
      __syncthreads();
#pragma unroll
      for (int kt2 = 0; kt2 < 10; ++kt2) {
        const int kt = hh * 10 + kt2;
#pragma unroll
        for (int r = 0; r < 4; ++r)
          Ps[w][(qd * 4 + r) * 168 + kt2 * 16 + m16] = f2bf(acc[kt][r] * rl[r]);
      }
      __syncthreads();
#pragma unroll
      for (int ks = 0; ks < 5; ++ks) {
        const bf16x8 pf = *(const bf16x8*)&Ps[w][m16 * 168 + ks * 32 + qd * 8];
        const bf16x8 v0 =
            *(const bf16x8*)&Vt[m16 * 328 + hh * 160 + ks * 32 + qd * 8];
        const bf16x8 v1 =
            *(const bf16x8*)&Vt[(16 + m16) * 328 + hh * 160 + ks * 32 + qd * 8];
        accO0 = __builtin_amdgcn_mfma_f32_16x16x32_bf16(pf, v0, accO0, 0, 0, 0);
        accO1 = __builtin_amdgcn_mfma_f32_16x16x32_bf16(pf, v1, accO1, 0, 0, 0);
      }
    }

#pragma unroll
    for (int r = 0; r < 4; ++r) {
      const int j = jt * 16 + qd * 4 + r;
      const float g0 = bf2f(Gg[base + (size_t)j * 32 + m16]);
      const float g1 = bf2f(Gg[base + (size_t)j * 32 + 16 + m16]);
      unsigned short* op = Obg + (size_t)(i * 320 + j) * 128 + h * 32;
      op[m16]      = f2bf(g0 * accO0[r]);
      op[16 + m16] = f2bf(g1 * accO1[r]);
    }
  }
}

// ---------------------------------------------------------------------------
// Kernel 3: output GEMM dz = Obg @ Woutt^T, * pair_mask. bf16 MFMA.
// M-tile 128, N-tile 64 (grid 2 x 800).
// ---------------------------------------------------------------------------
__global__ __launch_bounds__(256) void k_out(
    const unsigned short* __restrict__ Obg, const unsigned short* __restrict__ Woutt,
    const float* __restrict__ pm, float* __restrict__ out)
{
  __shared__ __attribute__((aligned(16))) unsigned short As[128 * 136];
  __shared__ __attribute__((aligned(16))) unsigned short Bs[64 * 136];
  const int t = threadIdx.x;
  const int ntile = blockIdx.x;   // 0..1
  const int m0 = blockIdx.y * 128;

  // ---- stage A (plain bf16 copy) ----
#pragma unroll
  for (int it = 0; it < 8; ++it) {
    const int idx = t + 256 * it;
    const int rr = idx >> 4, ck = idx & 15;
    const uint4 d = *(const uint4*)(Obg + (size_t)(m0 + rr) * 128 + ck * 8);
    *(uint4*)&As[rr * 136 + ck * 8] = d;
  }
  // ---- stage B ----
  {
    const unsigned short* wrow = Woutt + (size_t)ntile * 64 * 128;
#pragma unroll
    for (int it = 0; it < 4; ++it) {
      const int idx = t + 256 * it;
      const int n = idx >> 4, ck = idx & 15;
      const uint4 d = *(const uint4*)(wrow + n * 128 + ck * 8);
      *(uint4*)&Bs[n * 136 + ck * 8] = d;
    }
  }
  __syncthreads();

  const int w = t >> 6, lane = t & 63;
  const int m16 = lane & 15, qd = lane >> 4;
  const f32x4 z4 = {0.f, 0.f, 0.f, 0.f};
  f32x4 acc[2][4];
#pragma unroll
  for (int sub = 0; sub < 2; ++sub)
#pragma unroll
    for (int nt = 0; nt < 4; ++nt) acc[sub][nt] = z4;

#pragma unroll
  for (int ks = 0; ks < 4; ++ks) {
    const bf16x8 af0 = *(const bf16x8*)&As[(w * 32 + m16) * 136 + qd * 8 + ks * 32];
    const bf16x8 af1 = *(const bf16x8*)&As[(w * 32 + 16 + m16) * 136 + qd * 8 + ks * 32];
#pragma unroll
    for (int nt = 0; nt < 4; ++nt) {
      const bf16x8 bf = *(const bf16x8*)&Bs[(nt * 16 + m16) * 136 + qd * 8 + ks * 32];
      acc[0][nt] = __builtin_amdgcn_mfma_f32_16x16x32_bf16(af0, bf, acc[0][nt], 0, 0, 0);
      acc[1][nt] = __builtin_amdgcn_mfma_f32_16x16x32_bf16(af1, bf, acc[1][nt], 0, 0, 0);
    }
  }

#pragma unroll
  for (int sub = 0; sub < 2; ++sub) {
#pragma unroll
    for (int r = 0; r < 4; ++r) {
      const int p = m0 + w * 32 + sub * 16 + qd * 4 + r;
      const float m = pm[p];
      float* orow = out + (size_t)p * 128 + ntile * 64;
#pragma unroll
      for (int nt = 0; nt < 4; ++nt)
        orow[nt * 16 + m16] = acc[sub][nt][r] * m;
    }
  }
}

// ---------------------------------------------------------------------------
extern "C" void kernel_launch(void* const* d_in, const int* in_sizes, int n_in,
                              void* d_out, int out_size, void* d_ws, size_t ws_size,
                              hipStream_t stream)
{
  const float* z     = (const float*)d_in[0];
  const float* pmask = (const float*)d_in[1];
  const int*   rmask = (const int*)d_in[2];
  const float* gamma = (const float*)d_in[3];
  const float* beta  = (const float*)d_in[4];
  const float* Wq    = (const float*)d_in[5];
  const float* Wk    = (const float*)d_in[6];
  const float* Wv    = (const float*)d_in[7];
  const float* Wb    = (const float*)d_in[8];
  const float* Wg    = (const float*)d_in[9];
  const float* Wout  = (const float*)d_in[10];

  const size_t P = (size_t)LDIM * LDIM;        // 102400
  const size_t E = P * 128;                    // 13,107,200 elements
  char* ws = (char*)d_ws;
  unsigned short* Qg = (unsigned short*)ws;              // E bf16
  unsigned short* Kg = Qg + E;
  unsigned short* Vg = Kg + E;
  unsigned short* Gg = Vg + E;
  unsigned short* Obg = Gg + E;                          // E bf16
  unsigned short* Wt = Obg + E;                          // 576*128 bf16
  unsigned short* Woutt = Wt + 576 * 128;                // 128*128 bf16
  float* Bh = (float*)(Woutt + 128 * 128);               // 4*P fp32

  k_prep<<<dim3(11), 256, 0, stream>>>(Wq, Wk, Wv, Wb, Wg, Wout, Wt, Woutt);
  k_lnproj<<<dim3(9, 800), 256, 0, stream>>>(z, gamma, beta, Wt,
                                             Qg, Kg, Vg, Gg, Bh);
  k_attn<<<dim3(NH, LDIM), 256, 0, stream>>>(Qg, Kg, Vg, Gg, Bh, rmask, Obg);
  k_out<<<dim3(2, 800), 256, 0, stream>>>(Obg, Woutt, pmask, (float*)d_out);
}

// Round 5
// 352.365 us; speedup vs baseline: 4.1338x; 1.1495x over previous
//
#include <hip/hip_runtime.h>

#define LDIM 320
#define CZ 128
#define NH 4
#define CH 32
#define SCALE_QK 0.17677669529663687f  // 1/sqrt(32)
#define LN_EPS 1e-5f

typedef __attribute__((ext_vector_type(8))) short bf16x8;
typedef __attribute__((ext_vector_type(4))) float f32x4;

__device__ __forceinline__ unsigned int pack_bf2(float a, float b) {
  unsigned int ua = __float_as_uint(a);
  unsigned int ub = __float_as_uint(b);
  unsigned int ra = (ua + 0x7fffu + ((ua >> 16) & 1u)) >> 16;   // RNE bf16
  unsigned int rb = (ub + 0x7fffu + ((ub >> 16) & 1u)) >> 16;
  return (ra & 0xffffu) | (rb << 16);
}

__device__ __forceinline__ unsigned short f2bf(float a) {
  unsigned int ua = __float_as_uint(a);
  return (unsigned short)((ua + 0x7fffu + ((ua >> 16) & 1u)) >> 16);
}

__device__ __forceinline__ float bf2f(unsigned short u) {
  return __uint_as_float(((unsigned int)u) << 16);
}

// ---------------------------------------------------------------------------
// Kernel 0: weight prep. Wt[576][128] bf16 = [Wq|Wk|Wv|Wg|Wb|0] transposed;
// Woutt[128][128] bf16 = Wout transposed. Runs once per launch (11 blocks).
// ---------------------------------------------------------------------------
__global__ __launch_bounds__(256) void k_prep(
    const float* __restrict__ Wq, const float* __restrict__ Wk,
    const float* __restrict__ Wv, const float* __restrict__ Wb,
    const float* __restrict__ Wg, const float* __restrict__ Wout,
    unsigned short* __restrict__ Wt, unsigned short* __restrict__ Woutt)
{
  __shared__ __attribute__((aligned(16))) unsigned short buf[64 * 136];
  const int t = threadIdx.x, bid = blockIdx.x;
  const bool isOut = (bid >= 9);
  const int n0 = isOut ? (bid - 9) * 64 : bid * 64;
  const int nl = t & 63;
  const int n = n0 + nl;
#pragma unroll 8
  for (int it = 0; it < 32; ++it) {
    const int k = (t >> 6) + 4 * it;
    float v;
    if (isOut)        v = Wout[k * 128 + n];
    else if (n < 128) v = Wq[k * 128 + n];
    else if (n < 256) v = Wk[k * 128 + n - 128];
    else if (n < 384) v = Wv[k * 128 + n - 256];
    else if (n < 512) v = Wg[k * 128 + n - 384];
    else if (n < 516) v = Wb[k * 4 + n - 512];
    else              v = 0.f;
    buf[nl * 136 + k] = f2bf(v);
  }
  __syncthreads();
  unsigned short* dst = isOut ? Woutt : Wt;
#pragma unroll
  for (int it = 0; it < 4; ++it) {
    const int idx = t + 256 * it;
    const int rr = idx >> 4, ck = idx & 15;
    const uint4 d = *(const uint4*)&buf[rr * 136 + ck * 8];
    *(uint4*)(dst + (size_t)(n0 + rr) * 128 + ck * 8) = d;
  }
}

// ---------------------------------------------------------------------------
// Kernel 1: fused LayerNorm + all projections, bf16 MFMA GEMM.
// One block per 128-row M-tile (grid 800). z read ONCE; LN once per row;
// A-frags preloaded to registers once; B-frags straight from global Wt
// (L1/L2-resident, per the verified k_attn K-frag pattern). No Bs LDS.
// ---------------------------------------------------------------------------
__global__ __launch_bounds__(256) void k_lnproj(
    const float* __restrict__ z, const float* __restrict__ gamma,
    const float* __restrict__ beta, const unsigned short* __restrict__ Wt,
    unsigned short* __restrict__ Qg, unsigned short* __restrict__ Kg,
    unsigned short* __restrict__ Vg, unsigned short* __restrict__ Gg,
    float* __restrict__ Bh)
{
  __shared__ __attribute__((aligned(16))) unsigned short As[128 * 136]; // 34.8KB
  const int t = threadIdx.x;
  const int m0 = blockIdx.x * 128;
  const int rlane = t & 7;            // 8 lanes per row, 16 cols each

  // gamma/beta for this lane's 16 columns (loop-invariant)
  const float* gp = gamma + rlane * 16;
  const float* bp = beta + rlane * 16;
  const float4 g0 = *(const float4*)(gp + 0);
  const float4 g1 = *(const float4*)(gp + 4);
  const float4 g2 = *(const float4*)(gp + 8);
  const float4 g3 = *(const float4*)(gp + 12);
  const float4 b0 = *(const float4*)(bp + 0);
  const float4 b1 = *(const float4*)(bp + 4);
  const float4 b2 = *(const float4*)(bp + 8);
  const float4 b3 = *(const float4*)(bp + 12);

  // ---- stage z -> LN -> bf16 As, coalesced (8 lanes/row) ----
#pragma unroll
  for (int rr = 0; rr < 4; ++rr) {
    const int row = rr * 32 + (t >> 3);
    const float* zp = z + (size_t)(m0 + row) * CZ + rlane * 16;
    const float4 x0 = *(const float4*)(zp + 0);
    const float4 x1 = *(const float4*)(zp + 4);
    const float4 x2 = *(const float4*)(zp + 8);
    const float4 x3 = *(const float4*)(zp + 12);
    float s  = x0.x + x0.y + x0.z + x0.w + x1.x + x1.y + x1.z + x1.w +
               x2.x + x2.y + x2.z + x2.w + x3.x + x3.y + x3.z + x3.w;
    float ss = x0.x*x0.x + x0.y*x0.y + x0.z*x0.z + x0.w*x0.w +
               x1.x*x1.x + x1.y*x1.y + x1.z*x1.z + x1.w*x1.w +
               x2.x*x2.x + x2.y*x2.y + x2.z*x2.z + x2.w*x2.w +
               x3.x*x3.x + x3.y*x3.y + x3.z*x3.z + x3.w*x3.w;
    s  += __shfl_xor(s, 1);  ss += __shfl_xor(ss, 1);
    s  += __shfl_xor(s, 2);  ss += __shfl_xor(ss, 2);
    s  += __shfl_xor(s, 4);  ss += __shfl_xor(ss, 4);
    const float mu  = s * (1.f / 128.f);
    const float var = ss * (1.f / 128.f) - mu * mu;
    const float rs  = rsqrtf(var + LN_EPS);
    uint4 u0, u1;
    u0.x = pack_bf2((x0.x - mu) * rs * g0.x + b0.x, (x0.y - mu) * rs * g0.y + b0.y);
    u0.y = pack_bf2((x0.z - mu) * rs * g0.z + b0.z, (x0.w - mu) * rs * g0.w + b0.w);
    u0.z = pack_bf2((x1.x - mu) * rs * g1.x + b1.x, (x1.y - mu) * rs * g1.y + b1.y);
    u0.w = pack_bf2((x1.z - mu) * rs * g1.z + b1.z, (x1.w - mu) * rs * g1.w + b1.w);
    u1.x = pack_bf2((x2.x - mu) * rs * g2.x + b2.x, (x2.y - mu) * rs * g2.y + b2.y);
    u1.y = pack_bf2((x2.z - mu) * rs * g2.z + b2.z, (x2.w - mu) * rs * g2.w + b2.w);
    u1.z = pack_bf2((x3.x - mu) * rs * g3.x + b3.x, (x3.y - mu) * rs * g3.y + b3.y);
    u1.w = pack_bf2((x3.z - mu) * rs * g3.z + b3.z, (x3.w - mu) * rs * g3.w + b3.w);
    unsigned short* dst = &As[row * 136 + rlane * 16];
    *(uint4*)(dst + 0) = u0;
    *(uint4*)(dst + 8) = u1;
  }
  __syncthreads();

  const int w = t >> 6, lane = t & 63;
  const int m16 = lane & 15, qd = lane >> 4;
  const f32x4 z4 = {0.f, 0.f, 0.f, 0.f};

  // ---- preload A-frags once (2 sub-tiles x 4 k-steps = 32 VGPRs) ----
  bf16x8 af[2][4];
#pragma unroll
  for (int ks = 0; ks < 4; ++ks) {
    af[0][ks] = *(const bf16x8*)&As[(w * 32 + m16) * 136 + ks * 32 + qd * 8];
    af[1][ks] = *(const bf16x8*)&As[(w * 32 + 16 + m16) * 136 + ks * 32 + qd * 8];
  }

  // ---- 8 output n-tiles (Q/K/V/G), B-frags from global ----
  for (int ntile = 0; ntile < 8; ++ntile) {
    f32x4 acc[2][4];
#pragma unroll
    for (int sub = 0; sub < 2; ++sub)
#pragma unroll
      for (int nt = 0; nt < 4; ++nt) acc[sub][nt] = z4;
#pragma unroll
    for (int ks = 0; ks < 4; ++ks) {
#pragma unroll
      for (int nt = 0; nt < 4; ++nt) {
        const bf16x8 bf = *(const bf16x8*)(
            Wt + (size_t)(ntile * 64 + nt * 16 + m16) * 128 + ks * 32 + qd * 8);
        acc[0][nt] = __builtin_amdgcn_mfma_f32_16x16x32_bf16(af[0][ks], bf, acc[0][nt], 0, 0, 0);
        acc[1][nt] = __builtin_amdgcn_mfma_f32_16x16x32_bf16(af[1][ks], bf, acc[1][nt], 0, 0, 0);
      }
    }
    // epilogue: C row = qd*4+r -> p, col = m16 -> n  (verified round-4 mapping)
#pragma unroll
    for (int sub = 0; sub < 2; ++sub) {
#pragma unroll
      for (int r = 0; r < 4; ++r) {
        const int p = m0 + w * 32 + sub * 16 + qd * 4 + r;
        const int a = p / 320, bb = p - a * 320;
#pragma unroll
        for (int nt = 0; nt < 4; ++nt) {
          const int n = ntile * 64 + nt * 16 + m16;
          const int off = n & 127, hh = off >> 5, cc = off & 31;
          float val = acc[sub][nt][r];
          if (ntile >= 6) val = 1.f / (1.f + __expf(-val));  // sigmoid for G
          unsigned short* dst =
              (ntile < 2 ? Qg : (ntile < 4 ? Kg : (ntile < 6 ? Vg : Gg)));
          dst[((size_t)(a * 4 + hh) * 320 + bb) * 32 + cc] = f2bf(val);
        }
      }
    }
  }

  // ---- bias tile (Wt rows 512..527; cols 516+ are zero-padded) ----
  {
    f32x4 acc0 = z4, acc1 = z4;
#pragma unroll
    for (int ks = 0; ks < 4; ++ks) {
      const bf16x8 bf = *(const bf16x8*)(
          Wt + (size_t)(512 + m16) * 128 + ks * 32 + qd * 8);
      acc0 = __builtin_amdgcn_mfma_f32_16x16x32_bf16(af[0][ks], bf, acc0, 0, 0, 0);
      acc1 = __builtin_amdgcn_mfma_f32_16x16x32_bf16(af[1][ks], bf, acc1, 0, 0, 0);
    }
    if (m16 < 4) {
#pragma unroll
      for (int r = 0; r < 4; ++r) {
        const int p0 = m0 + w * 32 + qd * 4 + r;
        Bh[(size_t)m16 * 102400 + p0] = acc0[r];
        Bh[(size_t)m16 * 102400 + p0 + 16] = acc1[r];
      }
    }
  }
}

// ---------------------------------------------------------------------------
// Kernel 2: MFMA attention (verified round 4, unchanged).
// ---------------------------------------------------------------------------
__global__ __launch_bounds__(256) void k_attn(
    const unsigned short* __restrict__ Qg, const unsigned short* __restrict__ Kg,
    const unsigned short* __restrict__ Vg, const unsigned short* __restrict__ Gg,
    const float* __restrict__ Bh, const int* __restrict__ rmask,
    unsigned short* __restrict__ Obg)
{
  __shared__ __attribute__((aligned(16))) unsigned short Vt[32 * 328];     // [c][k]
  __shared__ __attribute__((aligned(16))) unsigned short Ps[4][16 * 168];  // per-wave
  const int h = blockIdx.x, i = blockIdx.y;
  const int t = threadIdx.x;
  const size_t base = (size_t)(i * NH + h) * (LDIM * CH);

  // ---- stage V transposed [c][k] ----
  {
    const int k0 = t >> 3, c4 = (t & 7) * 4;
#pragma unroll
    for (int it = 0; it < 10; ++it) {
      const int k = k0 + 32 * it;
      const uint2 d = *(const uint2*)(Vg + base + k * 32 + c4);
      Vt[(c4 + 0) * 328 + k] = (unsigned short)(d.x & 0xffffu);
      Vt[(c4 + 1) * 328 + k] = (unsigned short)(d.x >> 16);
      Vt[(c4 + 2) * 328 + k] = (unsigned short)(d.y & 0xffffu);
      Vt[(c4 + 3) * 328 + k] = (unsigned short)(d.y >> 16);
    }
  }
  __syncthreads();

  const int w = t >> 6, lane = t & 63;
  const int m16 = lane & 15, qd = lane >> 4;
  const f32x4 z4 = {0.f, 0.f, 0.f, 0.f};

  float mkr[20];
#pragma unroll
  for (int kt = 0; kt < 20; ++kt)
    mkr[kt] = rmask[kt * 16 + m16] ? 0.f : -INFINITY;

  for (int jt = w; jt < 20; jt += 4) {
    const bf16x8 qfrag =
        *(const bf16x8*)(Qg + base + (size_t)(jt * 16 + m16) * 32 + qd * 8);

    f32x4 acc[20];
#pragma unroll
    for (int kt = 0; kt < 20; ++kt) {
      const bf16x8 kf =
          *(const bf16x8*)(Kg + base + (size_t)(kt * 16 + m16) * 32 + qd * 8);
      acc[kt] = __builtin_amdgcn_mfma_f32_16x16x32_bf16(qfrag, kf, z4, 0, 0, 0);
    }

    const float* bp = Bh + (size_t)h * 102400 +
                      (size_t)(jt * 16 + qd * 4) * 320 + m16;
    float mx[4] = {-INFINITY, -INFINITY, -INFINITY, -INFINITY};
#pragma unroll
    for (int kt = 0; kt < 20; ++kt) {
#pragma unroll
      for (int r = 0; r < 4; ++r) {
        const float b = bp[r * 320 + kt * 16];
        const float s = fmaf(acc[kt][r], SCALE_QK, b) + mkr[kt];
        acc[kt][r] = s;
        mx[r] = fmaxf(mx[r], s);
      }
    }
#pragma unroll
    for (int r = 0; r < 4; ++r) {
      mx[r] = fmaxf(mx[r], __shfl_xor(mx[r], 1));
      mx[r] = fmaxf(mx[r], __shfl_xor(mx[r], 2));
      mx[r] = fmaxf(mx[r], __shfl_xor(mx[r], 4));
      mx[r] = fmaxf(mx[r], __shfl_xor(mx[r], 8));
    }
    float l[4] = {0.f, 0.f, 0.f, 0.f};
#pragma unroll
    for (int kt = 0; kt < 20; ++kt) {
#pragma unroll
      for (int r = 0; r < 4; ++r) {
        const float p = __expf(acc[kt][r] - mx[r]);
        acc[kt][r] = p;
        l[r] += p;
      }
    }
#pragma unroll
    for (int r = 0; r < 4; ++r) {
      l[r] += __shfl_xor(l[r], 1);
      l[r] += __shfl_xor(l[r], 2);
      l[r] += __shfl_xor(l[r], 4);
      l[r] += __shfl_xor(l[r], 8);
    }
    float rl[4];
#pragma unroll
    for (int r = 0; r < 4; ++r) rl[r] = 1.f / l[r];

    f32x4 accO0 = z4, accO1 = z4;
#pragma unroll
    for (int hh = 0; hh < 2; ++hh) {
      __syncthreads();
#pragma unroll
      for (int kt2 = 0; kt2 < 10; ++kt2) {
        const int kt = hh * 10 + kt2;
#pragma unroll
        for (int r = 0; r < 4; ++r)
          Ps[w][(qd * 4 + r) * 168 + kt2 * 16 + m16] = f2bf(acc[kt][r] * rl[r]);
      }
      __syncthreads();
#pragma unroll
      for (int ks = 0; ks < 5; ++ks) {
        const bf16x8 pf = *(const bf16x8*)&Ps[w][m16 * 168 + ks * 32 + qd * 8];
        const bf16x8 v0 =
            *(const bf16x8*)&Vt[m16 * 328 + hh * 160 + ks * 32 + qd * 8];
        const bf16x8 v1 =
            *(const bf16x8*)&Vt[(16 + m16) * 328 + hh * 160 + ks * 32 + qd * 8];
        accO0 = __builtin_amdgcn_mfma_f32_16x16x32_bf16(pf, v0, accO0, 0, 0, 0);
        accO1 = __builtin_amdgcn_mfma_f32_16x16x32_bf16(pf, v1, accO1, 0, 0, 0);
      }
    }

#pragma unroll
    for (int r = 0; r < 4; ++r) {
      const int j = jt * 16 + qd * 4 + r;
      const float g0 = bf2f(Gg[base + (size_t)j * 32 + m16]);
      const float g1 = bf2f(Gg[base + (size_t)j * 32 + 16 + m16]);
      unsigned short* op = Obg + (size_t)(i * 320 + j) * 128 + h * 32;
      op[m16]      = f2bf(g0 * accO0[r]);
      op[16 + m16] = f2bf(g1 * accO1[r]);
    }
  }
}

// ---------------------------------------------------------------------------
// Kernel 3: output GEMM dz = Obg @ Woutt^T, * pair_mask. bf16 MFMA.
// (verified round 4, unchanged)
// ---------------------------------------------------------------------------
__global__ __launch_bounds__(256) void k_out(
    const unsigned short* __restrict__ Obg, const unsigned short* __restrict__ Woutt,
    const float* __restrict__ pm, float* __restrict__ out)
{
  __shared__ __attribute__((aligned(16))) unsigned short As[128 * 136];
  __shared__ __attribute__((aligned(16))) unsigned short Bs[64 * 136];
  const int t = threadIdx.x;
  const int ntile = blockIdx.x;   // 0..1
  const int m0 = blockIdx.y * 128;

#pragma unroll
  for (int it = 0; it < 8; ++it) {
    const int idx = t + 256 * it;
    const int rr = idx >> 4, ck = idx & 15;
    const uint4 d = *(const uint4*)(Obg + (size_t)(m0 + rr) * 128 + ck * 8);
    *(uint4*)&As[rr * 136 + ck * 8] = d;
  }
  {
    const unsigned short* wrow = Woutt + (size_t)ntile * 64 * 128;
#pragma unroll
    for (int it = 0; it < 4; ++it) {
      const int idx = t + 256 * it;
      const int n = idx >> 4, ck = idx & 15;
      const uint4 d = *(const uint4*)(wrow + n * 128 + ck * 8);
      *(uint4*)&Bs[n * 136 + ck * 8] = d;
    }
  }
  __syncthreads();

  const int w = t >> 6, lane = t & 63;
  const int m16 = lane & 15, qd = lane >> 4;
  const f32x4 z4 = {0.f, 0.f, 0.f, 0.f};
  f32x4 acc[2][4];
#pragma unroll
  for (int sub = 0; sub < 2; ++sub)
#pragma unroll
    for (int nt = 0; nt < 4; ++nt) acc[sub][nt] = z4;

#pragma unroll
  for (int ks = 0; ks < 4; ++ks) {
    const bf16x8 af0 = *(const bf16x8*)&As[(w * 32 + m16) * 136 + qd * 8 + ks * 32];
    const bf16x8 af1 = *(const bf16x8*)&As[(w * 32 + 16 + m16) * 136 + qd * 8 + ks * 32];
#pragma unroll
    for (int nt = 0; nt < 4; ++nt) {
      const bf16x8 bf = *(const bf16x8*)&Bs[(nt * 16 + m16) * 136 + qd * 8 + ks * 32];
      acc[0][nt] = __builtin_amdgcn_mfma_f32_16x16x32_bf16(af0, bf, acc[0][nt], 0, 0, 0);
      acc[1][nt] = __builtin_amdgcn_mfma_f32_16x16x32_bf16(af1, bf, acc[1][nt], 0, 0, 0);
    }
  }

#pragma unroll
  for (int sub = 0; sub < 2; ++sub) {
#pragma unroll
    for (int r = 0; r < 4; ++r) {
      const int p = m0 + w * 32 + sub * 16 + qd * 4 + r;
      const float m = pm[p];
      float* orow = out + (size_t)p * 128 + ntile * 64;
#pragma unroll
      for (int nt = 0; nt < 4; ++nt)
        orow[nt * 16 + m16] = acc[sub][nt][r] * m;
    }
  }
}

// ---------------------------------------------------------------------------
extern "C" void kernel_launch(void* const* d_in, const int* in_sizes, int n_in,
                              void* d_out, int out_size, void* d_ws, size_t ws_size,
                              hipStream_t stream)
{
  const float* z     = (const float*)d_in[0];
  const float* pmask = (const float*)d_in[1];
  const int*   rmask = (const int*)d_in[2];
  const float* gamma = (const float*)d_in[3];
  const float* beta  = (const float*)d_in[4];
  const float* Wq    = (const float*)d_in[5];
  const float* Wk    = (const float*)d_in[6];
  const float* Wv    = (const float*)d_in[7];
  const float* Wb    = (const float*)d_in[8];
  const float* Wg    = (const float*)d_in[9];
  const float* Wout  = (const float*)d_in[10];

  const size_t P = (size_t)LDIM * LDIM;        // 102400
  const size_t E = P * 128;                    // 13,107,200 elements
  char* ws = (char*)d_ws;
  unsigned short* Qg = (unsigned short*)ws;              // E bf16
  unsigned short* Kg = Qg + E;
  unsigned short* Vg = Kg + E;
  unsigned short* Gg = Vg + E;
  unsigned short* Obg = Gg + E;                          // E bf16
  unsigned short* Wt = Obg + E;                          // 576*128 bf16
  unsigned short* Woutt = Wt + 576 * 128;                // 128*128 bf16
  float* Bh = (float*)(Woutt + 128 * 128);               // 4*P fp32

  k_prep<<<dim3(11), 256, 0, stream>>>(Wq, Wk, Wv, Wb, Wg, Wout, Wt, Woutt);
  k_lnproj<<<dim3(800), 256, 0, stream>>>(z, gamma, beta, Wt,
                                          Qg, Kg, Vg, Gg, Bh);
  k_attn<<<dim3(NH, LDIM), 256, 0, stream>>>(Qg, Kg, Vg, Gg, Bh, rmask, Obg);
  k_out<<<dim3(2, 800), 256, 0, stream>>>(Obg, Woutt, pmask, (float*)d_out);
}